// Round 18
// baseline (184.606 us; speedup 1.0000x reference)
//
#include <hip/hip_runtime.h>
#include <hip/hip_bf16.h>
#include <stdint.h>

#define BB 2
#define SS 2048
#define HH 1024
#define NHH 16
#define HDD 64
#define MM (BB*SS)      // 4096
#define N1 (3*HH)       // 3072
#define NT (SS/64)      // 32 kv tiles
#define LOG2E 1.44269504f

using bf16 = __hip_bfloat16;
typedef __attribute__((ext_vector_type(8))) short bf16x8;
typedef __attribute__((ext_vector_type(4))) float f32x4;

__device__ inline unsigned short f2bfu(float f) {
  union { bf16 h; unsigned short u; } c;
  c.h = __float2bfloat16(f);
  return c.u;
}

__device__ inline unsigned int cvtpk(float lo, float hi) {
  unsigned int r;
  asm("v_cvt_pk_bf16_f32 %0, %1, %2" : "=v"(r) : "v"(lo), "v"(hi));
  return r;
}

__device__ inline void load_lds16(const void* g, void* l) {
  __builtin_amdgcn_global_load_lds(
      (const __attribute__((address_space(1))) void*)g,
      (__attribute__((address_space(3))) void*)l, 16, 0, 0);
}

__device__ inline f32x4 mfma16(bf16x8 a, bf16x8 b, f32x4 c) {
  return __builtin_amdgcn_mfma_f32_16x16x32_bf16(a, b, c, 0, 0, 0);
}

// ---------------- prep: mask tile flags (blocks 0..2047) + fp32->bf16 cvt ----------
__global__ __launch_bounds__(256) void prep_kernel(const float* __restrict__ mask,
                                                   unsigned char* __restrict__ flags,
                                                   const float* __restrict__ a,
                                                   unsigned short* __restrict__ ao, int na4,
                                                   const float* __restrict__ bsrc,
                                                   unsigned short* __restrict__ bo, int nb4,
                                                   const float* __restrict__ c,
                                                   unsigned short* __restrict__ co, int nc4) {
  if (blockIdx.x < 2048) {
    int t = blockIdx.x;
    int b = t >> 10, qt = (t >> 5) & 31, kt = t & 31;
    const float* mb = mask + ((size_t)b * SS + qt * 64) * SS + kt * 64;
    int row = threadIdx.x >> 2, c0 = (threadIdx.x & 3) * 16;
    int ok = 1;
#pragma unroll
    for (int j = 0; j < 4; ++j) {
      float4 v = *reinterpret_cast<const float4*>(mb + (size_t)row * SS + c0 + j * 4);
      ok &= (v.x == 1.f) & (v.y == 1.f) & (v.z == 1.f) & (v.w == 1.f);
    }
    ok = __all(ok);
    __shared__ int s[4];
    if ((threadIdx.x & 63) == 0) s[threadIdx.x >> 6] = ok;
    __syncthreads();
    if (threadIdx.x == 0) flags[t] = (unsigned char)(s[0] & s[1] & s[2] & s[3]);
    return;
  }
  int total = na4 + nb4 + nc4;
  int nblk = gridDim.x - 2048;
  int st = nblk * blockDim.x;
  for (int i = (blockIdx.x - 2048) * blockDim.x + threadIdx.x; i < total; i += st) {
    const float* in; unsigned short* out; int j = i;
    if (j < na4) { in = a; out = ao; }
    else if (j < na4 + nb4) { j -= na4; in = bsrc; out = bo; }
    else { j -= na4 + nb4; in = c; out = co; }
    float4 v = reinterpret_cast<const float4*>(in)[j];
    ushort4 o;
    o.x = f2bfu(v.x); o.y = f2bfu(v.y); o.z = f2bfu(v.z); o.w = f2bfu(v.w);
    reinterpret_cast<ushort4*>(out)[j] = o;
  }
}

// ---------------- V transpose: mixed V-cols -> vT[b][h][d][s] ----------------
__global__ __launch_bounds__(256) void vtrans_kernel(const unsigned short* __restrict__ mixed,
                                                     unsigned short* __restrict__ vT) {
  __shared__ unsigned short t[64 * 72];
  const int st = blockIdx.x, bh = blockIdx.y;
  const int b = bh >> 4, h = bh & 15;
  const int r = threadIdx.x >> 2, c0 = (threadIdx.x & 3) * 16;

  const unsigned short* src = mixed + ((size_t)(b * SS) + st * 64) * N1 + h * 192 + 128;
  union { bf16x8 v; unsigned short u[8]; } A, B;
  A.v = *reinterpret_cast<const bf16x8*>(src + (size_t)r * N1 + c0);
  B.v = *reinterpret_cast<const bf16x8*>(src + (size_t)r * N1 + c0 + 8);
#pragma unroll
  for (int j = 0; j < 8; ++j) t[(c0 + j) * 72 + r] = A.u[j];
#pragma unroll
  for (int j = 0; j < 8; ++j) t[(c0 + 8 + j) * 72 + r] = B.u[j];
  __syncthreads();

  unsigned short* dst = vT + ((size_t)bh * HDD + r) * SS + st * 64 + c0;
  bf16x8 o0 = *reinterpret_cast<const bf16x8*>(&t[r * 72 + c0]);
  bf16x8 o1 = *reinterpret_cast<const bf16x8*>(&t[r * 72 + c0 + 8]);
  *reinterpret_cast<bf16x8*>(dst) = o0;
  *reinterpret_cast<bf16x8*>(dst + 8) = o1;
}

// ---------------- GEMM (R13, verified): 128x128, BK=64, XOR-swizzled LDS ------------
template <bool OUT_BF16>
__global__ __launch_bounds__(256) void gemm_bt(const unsigned short* __restrict__ A,
                                               const unsigned short* __restrict__ Bt,
                                               const float* __restrict__ bias,
                                               void* __restrict__ Cv,
                                               int Ndim, int Kdim) {
  __shared__ __align__(16) unsigned short As[128 * 64];
  __shared__ __align__(16) unsigned short Bs[128 * 64];

  const int tid = threadIdx.x;
  const int wave = tid >> 6, lane = tid & 63;
  const int m0 = blockIdx.x * 128;
  const int n0 = blockIdx.y * 128;
  const int wm = (wave >> 1) * 64, wn = (wave & 1) * 64;
  const int lrow = lane & 15;
  const int g = lane >> 4;
  const int r4 = (lane >> 4) * 4;
  const int x0 = (g ^ (lrow & 7)) << 3;
  const int x1 = ((g + 4) ^ (lrow & 7)) << 3;

  f32x4 acc[4][4];
  const f32x4 z = {0.f, 0.f, 0.f, 0.f};
  for (int i = 0; i < 4; ++i)
    for (int j = 0; j < 4; ++j) acc[i][j] = z;

  for (int k0 = 0; k0 < Kdim; k0 += 64) {
#pragma unroll
    for (int it = 0; it < 4; ++it) {
      int idx = it * 256 + tid;
      int row = idx >> 3, seg = idx & 7;
      int sw = (seg ^ (row & 7)) << 3;
      load_lds16(A + (size_t)(m0 + row) * Kdim + k0 + sw, &As[row * 64 + seg * 8]);
      load_lds16(Bt + (size_t)(n0 + row) * Kdim + k0 + sw, &Bs[row * 64 + seg * 8]);
    }
    __syncthreads();

    bf16x8 af[4], bfr[4];
#pragma unroll
    for (int i = 0; i < 4; ++i)
      af[i] = *reinterpret_cast<const bf16x8*>(&As[(wm + i * 16 + lrow) * 64 + x0]);
#pragma unroll
    for (int j = 0; j < 4; ++j)
      bfr[j] = *reinterpret_cast<const bf16x8*>(&Bs[(wn + j * 16 + lrow) * 64 + x0]);
#pragma unroll
    for (int i = 0; i < 4; ++i)
#pragma unroll
      for (int j = 0; j < 4; ++j)
        acc[i][j] = mfma16(af[i], bfr[j], acc[i][j]);
#pragma unroll
    for (int i = 0; i < 4; ++i)
      af[i] = *reinterpret_cast<const bf16x8*>(&As[(wm + i * 16 + lrow) * 64 + x1]);
#pragma unroll
    for (int j = 0; j < 4; ++j)
      bfr[j] = *reinterpret_cast<const bf16x8*>(&Bs[(wn + j * 16 + lrow) * 64 + x1]);
#pragma unroll
    for (int i = 0; i < 4; ++i)
#pragma unroll
      for (int j = 0; j < 4; ++j)
        acc[i][j] = mfma16(af[i], bfr[j], acc[i][j]);
    __syncthreads();
  }

#pragma unroll
  for (int i = 0; i < 4; ++i) {
#pragma unroll
    for (int j = 0; j < 4; ++j) {
      int col = n0 + wn + j * 16 + lrow;
      float bv = bias[col];
#pragma unroll
      for (int r = 0; r < 4; ++r) {
        int row = m0 + wm + i * 16 + r4 + r;
        float v = acc[i][j][r] + bv;
        if (OUT_BF16) {
          ((unsigned short*)Cv)[(size_t)row * Ndim + col] = f2bfu(v);
        } else {
          ((float*)Cv)[(size_t)row * Ndim + col] = v;
        }
      }
    }
  }
}

// ---------------- Flash attention: tile-parity split-K, 2 subtiles/wave -------------
// Block 256 = 4 waves, 64 q-rows, grid (32, B*NH) = 1024 blocks (4/CU, 40KB LDS).
// Wave w: rows rb=(w&1)*32 .. +31 (subtiles A: rb..rb+15, B: rb+16..rb+31),
// computes only tiles with parity p=w>>1 (buf = parity). K/V frags read ONCE per
// wave-tile, feed both subtiles (28 LDS ops / 32 rows vs R9's 22/16). Max-free
// softmax (R9-verified) => split-K merge = pure add (R15/16-verified math).
__global__ __launch_bounds__(256, 4) void attn_kernel(const unsigned short* __restrict__ mixed,
                                                      const unsigned short* __restrict__ vT,
                                                      const float* __restrict__ mask,
                                                      const unsigned char* __restrict__ flags,
                                                      unsigned short* __restrict__ ctx) {
  __shared__ __align__(16) unsigned short Ks[2][64 * 64];
  __shared__ __align__(16) unsigned short Vt[2][64 * 64];   // [d][s]
  __shared__ __align__(16) unsigned short QP[64 * 64];      // Q tile, then P (per-wave)

  const int tid = threadIdx.x, wave = tid >> 6, lane = tid & 63;
  const int ql = lane & 15;
  const int g = lane >> 4;
  const int pair = wave >> 1;          // tile parity this wave computes
  const int rb = (wave & 1) * 32;      // row base within 64-row Q block
  const int q0 = blockIdx.x * 64;
  const int bh = blockIdx.y;
  const int b = bh / NHH, hh = bh % NHH;

  const unsigned short* qbase = mixed + (size_t)(b * SS) * N1 + hh * 192;
  const unsigned short* kbase = qbase + 64;
  const unsigned short* vtbase = vT + ((size_t)(b * NHH + hh) * HDD) * SS;  // [d][s]
  const float* mbase = mask + (size_t)b * SS * SS;
  const unsigned char* fl = flags + ((size_t)b * 32 + blockIdx.x) * 32;

  const int srow = tid >> 3, sseg = tid & 7;
  const int swst = (sseg ^ (srow & 7)) << 3;

  // ---- prologue: stage Q, K0, V0 (tile 0 -> buf 0) ----
  load_lds16(qbase + (size_t)(q0 + srow) * N1 + swst, &QP[srow * 64 + sseg * 8]);
  load_lds16(qbase + (size_t)(q0 + 32 + srow) * N1 + swst, &QP[(32 + srow) * 64 + sseg * 8]);
  load_lds16(kbase + (size_t)srow * N1 + swst, &Ks[0][srow * 64 + sseg * 8]);
  load_lds16(kbase + (size_t)(32 + srow) * N1 + swst, &Ks[0][(32 + srow) * 64 + sseg * 8]);
  load_lds16(vtbase + (size_t)srow * SS + swst, &Vt[0][srow * 64 + sseg * 8]);
  load_lds16(vtbase + (size_t)(32 + srow) * SS + swst, &Vt[0][(32 + srow) * 64 + sseg * 8]);
  __syncthreads();

  // ---- hoist Q fragments for both subtiles ----
  const int qrA = rb + ql, qrB = rb + 16 + ql;
  const bf16x8 qfA0 = *reinterpret_cast<const bf16x8*>(&QP[qrA * 64 + ((g ^ (qrA & 7)) << 3)]);
  const bf16x8 qfA1 = *reinterpret_cast<const bf16x8*>(&QP[qrA * 64 + (((g + 4) ^ (qrA & 7)) << 3)]);
  const bf16x8 qfB0 = *reinterpret_cast<const bf16x8*>(&QP[qrB * 64 + ((g ^ (qrB & 7)) << 3)]);
  const bf16x8 qfB1 = *reinterpret_cast<const bf16x8*>(&QP[qrB * 64 + (((g + 4) ^ (qrB & 7)) << 3)]);
  __syncthreads();   // everyone done reading Q before P overwrites it

  // ---- precomputed loop-invariant LDS pointers ----
  const int s0 = (g ^ (ql & 7)) << 3;
  const int s1 = ((g + 4) ^ (ql & 7)) << 3;
  const unsigned short* KrA = &Ks[0][ql * 64 + s0];   // + CUR*4096 + n*1024
  const unsigned short* KrB = &Ks[0][ql * 64 + s1];
  const unsigned short* VrA = &Vt[0][ql * 64 + s0];   // + CUR*4096 + fd*1024
  const unsigned short* VrB = &Vt[0][ql * 64 + s1];
  unsigned short* Ps = &QP[wave * 1024];
  const int X = (ql & 7) << 3;
  unsigned short* Pw0 = &Ps[ql * 64 + ((4 * g) ^ X)];
  unsigned short* Pw1 = &Ps[ql * 64 + ((16 + 4 * g) ^ X)];
  unsigned short* Pw2 = &Ps[ql * 64 + ((32 + 4 * g) ^ X)];
  unsigned short* Pw3 = &Ps[ql * 64 + ((48 + 4 * g) ^ X)];
  const unsigned short* Pr0 = &Ps[ql * 64 + ((8 * g) ^ X)];
  const unsigned short* Pr1 = &Ps[ql * 64 + ((32 + 8 * g) ^ X)];

  // ---- loop-carried global prefetch pointers (point at tile 1) ----
  const unsigned short* kpre = kbase + (size_t)(64 + srow) * N1 + swst;
  const unsigned short* vpre = vtbase + (size_t)srow * SS + 64 + swst;

  f32x4 oaccA[4], oaccB[4];
  const f32x4 z = {0.f, 0.f, 0.f, 0.f};
  for (int fd = 0; fd < 4; ++fd) { oaccA[fd] = z; oaccB[fd] = z; }
  float lsumA = 0.f, lsumB = 0.f;
  const float C2 = 0.125f * LOG2E;

#define STAGE(NXT_)                                                             \
  {                                                                             \
    load_lds16(kpre, &Ks[NXT_][srow * 64 + sseg * 8]);                          \
    load_lds16(kpre + 32 * N1, &Ks[NXT_][(32 + srow) * 64 + sseg * 8]);         \
    load_lds16(vpre, &Vt[NXT_][srow * 64 + sseg * 8]);                          \
    load_lds16(vpre + 32 * SS, &Vt[NXT_][(32 + srow) * 64 + sseg * 8]);         \
    kpre += 64 * N1; vpre += 64;                                                \
  }

#define COMPUTE(CUR_, KT_)                                                      \
  {                                                                             \
    const int kt_ = (KT_);                                                      \
    f32x4 saccA[4], saccB[4];                                                   \
    __builtin_amdgcn_s_setprio(1);                                              \
    _Pragma("unroll")                                                           \
    for (int n = 0; n < 4; ++n) {                                               \
      bf16x8 k0 = *reinterpret_cast<const bf16x8*>(KrA + (CUR_)*4096 + n*1024); \
      bf16x8 k1 = *reinterpret_cast<const bf16x8*>(KrB + (CUR_)*4096 + n*1024); \
      saccA[n] = mfma16(k0, qfA0, z);                                           \
      saccA[n] = mfma16(k1, qfA1, saccA[n]);                                    \
      saccB[n] = mfma16(k0, qfB0, z);                                           \
      saccB[n] = mfma16(k1, qfB1, saccB[n]);                                    \
    }                                                                           \
    __builtin_amdgcn_s_setprio(0);                                              \
    const bool allones = fl[kt_] != 0;                                          \
    float pvA[4][4], pvB[4][4];                                                 \
    if (allones) {                                                              \
      _Pragma("unroll")                                                         \
      for (int n = 0; n < 4; ++n)                                               \
        _Pragma("unroll")                                                       \
        for (int r = 0; r < 4; ++r) {                                           \
          pvA[n][r] = exp2f(saccA[n][r] * C2);                                  \
          pvB[n][r] = exp2f(saccB[n][r] * C2);                                  \
        }                                                                       \
    } else {                                                                    \
      int qqA = q0 + rb + ql;                                                   \
      _Pragma("unroll")                                                         \
      for (int n = 0; n < 4; ++n)                                               \
        _Pragma("unroll")                                                       \
        for (int r = 0; r < 4; ++r) {                                           \
          int kk = kt_ * 64 + 16 * n + 4 * g + r;                               \
          float mvA = mbase[(size_t)qqA * SS + kk];                             \
          float mvB = mbase[(size_t)(qqA + 16) * SS + kk];                      \
          float sA = saccA[n][r] * 0.125f;                                      \
          float sB = saccB[n][r] * 0.125f;                                      \
          pvA[n][r] = exp2f((sA * mvA - 10000.f * (1.f - mvA)) * LOG2E);        \
          pvB[n][r] = exp2f((sB * mvB - 10000.f * (1.f - mvB)) * LOG2E);        \
        }                                                                       \
    }                                                                           \
    {                                                                           \
      float tA0 = (pvA[0][0] + pvA[0][1]) + (pvA[0][2] + pvA[0][3]);            \
      float tA1 = (pvA[1][0] + pvA[1][1]) + (pvA[1][2] + pvA[1][3]);            \
      float tA2 = (pvA[2][0] + pvA[2][1]) + (pvA[2][2] + pvA[2][3]);            \
      float tA3 = (pvA[3][0] + pvA[3][1]) + (pvA[3][2] + pvA[3][3]);            \
      lsumA += (tA0 + tA1) + (tA2 + tA3);                                       \
      float tB0 = (pvB[0][0] + pvB[0][1]) + (pvB[0][2] + pvB[0][3]);            \
      float tB1 = (pvB[1][0] + pvB[1][1]) + (pvB[1][2] + pvB[1][3]);            \
      float tB2 = (pvB[2][0] + pvB[2][1]) + (pvB[2][2] + pvB[2][3]);            \
      float tB3 = (pvB[3][0] + pvB[3][1]) + (pvB[3][2] + pvB[3][3]);            \
      lsumB += (tB0 + tB1) + (tB2 + tB3);                                       \
    }                                                                           \
    /* P round-trip: subtile A then B reuse the same wave-private region */     \
    { uint2 w; w.x = cvtpk(pvA[0][0], pvA[0][1]); w.y = cvtpk(pvA[0][2], pvA[0][3]); \
      *reinterpret_cast<uint2*>(Pw0) = w; }                                     \
    { uint2 w; w.x = cvtpk(pvA[1][0], pvA[1][1]); w.y = cvtpk(pvA[1][2], pvA[1][3]); \
      *reinterpret_cast<uint2*>(Pw1) = w; }                                     \
    { uint2 w; w.x = cvtpk(pvA[2][0], pvA[2][1]); w.y = cvtpk(pvA[2][2], pvA[2][3]); \
      *reinterpret_cast<uint2*>(Pw2) = w; }                                     \
    { uint2 w; w.x = cvtpk(pvA[3][0], pvA[3][1]); w.y = cvtpk(pvA[3][2], pvA[3][3]); \
      *reinterpret_cast<uint2*>(Pw3) = w; }                                     \
    bf16x8 paA0 = *reinterpret_cast<const bf16x8*>(Pr0);                        \
    bf16x8 paA1 = *reinterpret_cast<const bf16x8*>(Pr1);                        \
    { uint2 w; w.x = cvtpk(pvB[0][0], pvB[0][1]); w.y = cvtpk(pvB[0][2], pvB[0][3]); \
      *reinterpret_cast<uint2*>(Pw0) = w; }                                     \
    { uint2 w; w.x = cvtpk(pvB[1][0], pvB[1][1]); w.y = cvtpk(pvB[1][2], pvB[1][3]); \
      *reinterpret_cast<uint2*>(Pw1) = w; }                                     \
    { uint2 w; w.x = cvtpk(pvB[2][0], pvB[2][1]); w.y = cvtpk(pvB[2][2], pvB[2][3]); \
      *reinterpret_cast<uint2*>(Pw2) = w; }                                     \
    { uint2 w; w.x = cvtpk(pvB[3][0], pvB[3][1]); w.y = cvtpk(pvB[3][2], pvB[3][3]); \
      *reinterpret_cast<uint2*>(Pw3) = w; }                                     \
    bf16x8 paB0 = *reinterpret_cast<const bf16x8*>(Pr0);                        \
    bf16x8 paB1 = *reinterpret_cast<const bf16x8*>(Pr1);                        \
    /* PV: each V fragment read once, feeds both subtiles */                    \
    __builtin_amdgcn_s_setprio(1);                                              \
    _Pragma("unroll")                                                           \
    for (int fd = 0; fd < 4; ++fd) {                                            \
      bf16x8 bv0 = *reinterpret_cast<const bf16x8*>(VrA + (CUR_)*4096 + fd*1024); \
      bf16x8 bv1 = *reinterpret_cast<const bf16x8*>(VrB + (CUR_)*4096 + fd*1024); \
      oaccA[fd] = mfma16(paA0, bv0, oaccA[fd]);                                 \
      oaccA[fd] = mfma16(paA1, bv1, oaccA[fd]);                                 \
      oaccB[fd] = mfma16(paB0, bv0, oaccB[fd]);                                 \
      oaccB[fd] = mfma16(paB1, bv1, oaccB[fd]);                                 \
    }                                                                           \
    __builtin_amdgcn_s_setprio(0);                                              \
  }

  for (int kt = 0; kt < NT; kt += 2) {
    // even iter: stage tile kt+1 -> buf1; parity-0 waves compute tile kt (buf0)
    STAGE(1)                               // kt+1 <= 31 always
    if (pair == 0) COMPUTE(0, kt)
    __syncthreads();
    // odd iter: stage tile kt+2 -> buf0; parity-1 waves compute tile kt+1 (buf1)
    if (kt + 2 < NT) STAGE(0)
    if (pair == 1) COMPUTE(1, kt + 1)
    __syncthreads();
  }
#undef STAGE
#undef COMPUTE

  // ---- reduce l within wave (R9 pattern) ----
  lsumA += __shfl_xor(lsumA, 16, 64);
  lsumA += __shfl_xor(lsumA, 32, 64);
  lsumB += __shfl_xor(lsumB, 16, 64);
  lsumB += __shfl_xor(lsumB, 32, 64);

  // ---- split-K merge: parity-1 waves publish, parity-0 waves add + store ----
  float* Osh = reinterpret_cast<float*>(&Ks[0][0]);   // [64 rows][64 cols] fp32 = 16KB
  float* Lsh = reinterpret_cast<float*>(&Vt[0][0]);   // 64 floats
  if (pair == 1) {
#pragma unroll
    for (int r = 0; r < 4; ++r) {
      int rowA = rb + g * 4 + r, rowB = rb + 16 + g * 4 + r;
#pragma unroll
      for (int fd = 0; fd < 4; ++fd) {
        Osh[rowA * 64 + fd * 16 + ql] = oaccA[fd][r];
        Osh[rowB * 64 + fd * 16 + ql] = oaccB[fd][r];
      }
    }
    Lsh[rb + ql] = lsumA;        // redundant same-value writes across g,h: benign
    Lsh[rb + 16 + ql] = lsumB;
  }
  __syncthreads();
  if (pair == 0) {
#pragma unroll
    for (int r = 0; r < 4; ++r) {
      int rowA = rb + g * 4 + r, rowB = rb + 16 + g * 4 + r;
#pragma unroll
      for (int fd = 0; fd < 4; ++fd) {
        oaccA[fd][r] += Osh[rowA * 64 + fd * 16 + ql];
        oaccB[fd][r] += Osh[rowB * 64 + fd * 16 + ql];
      }
    }
    float lA = lsumA + Lsh[rb + ql];
    float lB = lsumB + Lsh[rb + 16 + ql];
    float invA = 1.f / lA;   // valid for q-row rb+ql at this lane
    float invB = 1.f / lB;
#pragma unroll
    for (int r = 0; r < 4; ++r) {
      float iA = __shfl(invA, g * 4 + r, 64);
      float iB = __shfl(invB, g * 4 + r, 64);
      int qqA = q0 + rb + g * 4 + r;
      unsigned short* cpA = ctx + (size_t)(b * SS + qqA) * HH + hh * HDD;
      unsigned short* cpB = ctx + (size_t)(b * SS + qqA + 16) * HH + hh * HDD;
#pragma unroll
      for (int fd = 0; fd < 4; ++fd) {
        cpA[fd * 16 + ql] = f2bfu(oaccA[fd][r] * iA);
        cpB[fd * 16 + ql] = f2bfu(oaccB[fd][r] * iB);
      }
    }
  }
}

extern "C" void kernel_launch(void* const* d_in, const int* in_sizes, int n_in,
                              void* d_out, int out_size, void* d_ws, size_t ws_size,
                              hipStream_t stream) {
  const float* hs      = (const float*)d_in[0];
  const float* mask    = (const float*)d_in[1];
  const float* qkv_w   = (const float*)d_in[2];
  const float* qkv_b   = (const float*)d_in[3];
  const float* dense_w = (const float*)d_in[4];
  const float* dense_b = (const float*)d_in[5];
  float* out = (float*)d_out;

  char* ws = (char*)d_ws;
  unsigned short* hs_b     = (unsigned short*)(ws);                 // 4096x1024 (8MB)
  unsigned short* qkvw_b   = (unsigned short*)(ws + 8388608);       // 3072x1024 (6MB)
  unsigned short* densew_b = (unsigned short*)(ws + 14680064);      // 1024x1024 (2MB)
  unsigned short* mixed_b  = (unsigned short*)(ws + 16777216);      // 4096x3072 (24MB)
  unsigned short* ctx_b    = (unsigned short*)(ws + 41943040);      // 4096x1024 (8MB)
  unsigned char*  flags    = (unsigned char*)(ws + 50331648);       // 2048 B
  unsigned short* vT_b     = (unsigned short*)(ws + 50335744);      // 8MB

  prep_kernel<<<4096, 256, 0, stream>>>(mask, flags,
                                        hs, hs_b, (MM * HH) / 4,
                                        qkv_w, qkvw_b, (N1 * HH) / 4,
                                        dense_w, densew_b, (HH * HH) / 4);

  gemm_bt<true><<<dim3(MM / 128, N1 / 128), 256, 0, stream>>>(
      hs_b, qkvw_b, qkv_b, mixed_b, N1, HH);

  vtrans_kernel<<<dim3(SS / 64, BB * NHH), 256, 0, stream>>>(mixed_b, vT_b);

  attn_kernel<<<dim3(SS / 64, BB * NHH), 256, 0, stream>>>(
      mixed_b, vT_b, mask, flags, ctx_b);

  gemm_bt<false><<<dim3(MM / 128, HH / 128), 256, 0, stream>>>(
      ctx_b, densew_b, dense_b, out, HH, HH);
}

// Round 19
// 150.534 us; speedup vs baseline: 1.2263x; 1.2263x over previous
//
#include <hip/hip_runtime.h>
#include <hip/hip_bf16.h>
#include <stdint.h>

#define BB 2
#define SS 2048
#define HH 1024
#define NHH 16
#define HDD 64
#define MM (BB*SS)      // 4096
#define N1 (3*HH)       // 3072
#define QKS 2048        // packed q/k row stride
#define NT (SS/64)      // 32 kv tiles
#define LOG2E 1.44269504f

using bf16 = __hip_bfloat16;
typedef __attribute__((ext_vector_type(8))) short bf16x8;
typedef __attribute__((ext_vector_type(4))) float f32x4;

__device__ inline unsigned short f2bfu(float f) {
  union { bf16 h; unsigned short u; } c;
  c.h = __float2bfloat16(f);
  return c.u;
}

__device__ inline unsigned int cvtpk(float lo, float hi) {
  unsigned int r;
  asm("v_cvt_pk_bf16_f32 %0, %1, %2" : "=v"(r) : "v"(lo), "v"(hi));
  return r;
}

__device__ inline void load_lds16(const void* g, void* l) {
  __builtin_amdgcn_global_load_lds(
      (const __attribute__((address_space(1))) void*)g,
      (__attribute__((address_space(3))) void*)l, 16, 0, 0);
}

__device__ inline f32x4 mfma16(bf16x8 a, bf16x8 b, f32x4 c) {
  return __builtin_amdgcn_mfma_f32_16x16x32_bf16(a, b, c, 0, 0, 0);
}

// ---------------- prep: mask tile flags (blocks 0..2047) + fp32->bf16 cvt ----------
__global__ __launch_bounds__(256) void prep_kernel(const float* __restrict__ mask,
                                                   unsigned char* __restrict__ flags,
                                                   const float* __restrict__ a,
                                                   unsigned short* __restrict__ ao, int na4,
                                                   const float* __restrict__ bsrc,
                                                   unsigned short* __restrict__ bo, int nb4,
                                                   const float* __restrict__ c,
                                                   unsigned short* __restrict__ co, int nc4) {
  if (blockIdx.x < 2048) {
    int t = blockIdx.x;
    int b = t >> 10, qt = (t >> 5) & 31, kt = t & 31;
    const float* mb = mask + ((size_t)b * SS + qt * 64) * SS + kt * 64;
    int row = threadIdx.x >> 2, c0 = (threadIdx.x & 3) * 16;
    int ok = 1;
#pragma unroll
    for (int j = 0; j < 4; ++j) {
      float4 v = *reinterpret_cast<const float4*>(mb + (size_t)row * SS + c0 + j * 4);
      ok &= (v.x == 1.f) & (v.y == 1.f) & (v.z == 1.f) & (v.w == 1.f);
    }
    ok = __all(ok);
    __shared__ int s[4];
    if ((threadIdx.x & 63) == 0) s[threadIdx.x >> 6] = ok;
    __syncthreads();
    if (threadIdx.x == 0) flags[t] = (unsigned char)(s[0] & s[1] & s[2] & s[3]);
    return;
  }
  int total = na4 + nb4 + nc4;
  int nblk = gridDim.x - 2048;
  int st = nblk * blockDim.x;
  for (int i = (blockIdx.x - 2048) * blockDim.x + threadIdx.x; i < total; i += st) {
    const float* in; unsigned short* out; int j = i;
    if (j < na4) { in = a; out = ao; }
    else if (j < na4 + nb4) { j -= na4; in = bsrc; out = bo; }
    else { j -= na4 + nb4; in = c; out = co; }
    float4 v = reinterpret_cast<const float4*>(in)[j];
    ushort4 o;
    o.x = f2bfu(v.x); o.y = f2bfu(v.y); o.z = f2bfu(v.z); o.w = f2bfu(v.w);
    reinterpret_cast<ushort4*>(out)[j] = o;
  }
}

// ---------------- GEMM-QK: qk[m][128*h + cc] = hs . qkv_w[192h+cc]^T + b ------------
// N-tile ny == head ny; B rows 192*ny .. +127 (contiguous). Out stride QKS.
__global__ __launch_bounds__(256) void gemm_qk(const unsigned short* __restrict__ A,
                                               const unsigned short* __restrict__ Bt,
                                               const float* __restrict__ bias,
                                               unsigned short* __restrict__ Out) {
  __shared__ __align__(16) unsigned short As[128 * 64];
  __shared__ __align__(16) unsigned short Bs[128 * 64];

  const int tid = threadIdx.x;
  const int wave = tid >> 6, lane = tid & 63;
  const int m0 = blockIdx.x * 128;
  const int n0 = blockIdx.y * 128;               // qk col base
  const int rbase = 192 * blockIdx.y;            // qkv_w row base
  const int wm = (wave >> 1) * 64, wn = (wave & 1) * 64;
  const int lrow = lane & 15;
  const int g = lane >> 4;
  const int r4 = g * 4;
  const int x0 = (g ^ (lrow & 7)) << 3;
  const int x1 = ((g + 4) ^ (lrow & 7)) << 3;

  f32x4 acc[4][4];
  const f32x4 z = {0.f, 0.f, 0.f, 0.f};
  for (int i = 0; i < 4; ++i)
    for (int j = 0; j < 4; ++j) acc[i][j] = z;

  for (int k0 = 0; k0 < HH; k0 += 64) {
#pragma unroll
    for (int it = 0; it < 4; ++it) {
      int idx = it * 256 + tid;
      int row = idx >> 3, seg = idx & 7;
      int sw = (seg ^ (row & 7)) << 3;
      load_lds16(A + (size_t)(m0 + row) * HH + k0 + sw, &As[row * 64 + seg * 8]);
      load_lds16(Bt + (size_t)(rbase + row) * HH + k0 + sw, &Bs[row * 64 + seg * 8]);
    }
    __syncthreads();

    bf16x8 af[4], bfr[4];
#pragma unroll
    for (int i = 0; i < 4; ++i)
      af[i] = *reinterpret_cast<const bf16x8*>(&As[(wm + i * 16 + lrow) * 64 + x0]);
#pragma unroll
    for (int j = 0; j < 4; ++j)
      bfr[j] = *reinterpret_cast<const bf16x8*>(&Bs[(wn + j * 16 + lrow) * 64 + x0]);
#pragma unroll
    for (int i = 0; i < 4; ++i)
#pragma unroll
      for (int j = 0; j < 4; ++j)
        acc[i][j] = mfma16(af[i], bfr[j], acc[i][j]);
#pragma unroll
    for (int i = 0; i < 4; ++i)
      af[i] = *reinterpret_cast<const bf16x8*>(&As[(wm + i * 16 + lrow) * 64 + x1]);
#pragma unroll
    for (int j = 0; j < 4; ++j)
      bfr[j] = *reinterpret_cast<const bf16x8*>(&Bs[(wn + j * 16 + lrow) * 64 + x1]);
#pragma unroll
    for (int i = 0; i < 4; ++i)
#pragma unroll
      for (int j = 0; j < 4; ++j)
        acc[i][j] = mfma16(af[i], bfr[j], acc[i][j]);
    __syncthreads();
  }

#pragma unroll
  for (int i = 0; i < 4; ++i) {
#pragma unroll
    for (int j = 0; j < 4; ++j) {
      int cl = wn + j * 16 + lrow;
      float bv = bias[rbase + cl];
#pragma unroll
      for (int r = 0; r < 4; ++r) {
        int row = m0 + wm + i * 16 + r4 + r;
        Out[(size_t)row * QKS + n0 + cl] = f2bfu(acc[i][j][r] + bv);
      }
    }
  }
}

// ---------------- GEMM-V: vT[b][head][d][s] = (hs . qkv_w[V rows]^T + b)^T ----------
// N-tile ny covers heads 2ny, 2ny+1 (64 V-cols each). Transposed LDS epilogue.
__global__ __launch_bounds__(256) void gemm_v(const unsigned short* __restrict__ A,
                                              const unsigned short* __restrict__ Bt,
                                              const float* __restrict__ bias,
                                              unsigned short* __restrict__ vT) {
  __shared__ __align__(16) unsigned short Sh[2 * 128 * 64];   // As | Bs, reused as Ct
  unsigned short* As = Sh;
  unsigned short* Bs = Sh + 128 * 64;

  const int tid = threadIdx.x;
  const int wave = tid >> 6, lane = tid & 63;
  const int m0 = blockIdx.x * 128;
  const int ny = blockIdx.y;
  const int wm = (wave >> 1) * 64, wn = (wave & 1) * 64;
  const int lrow = lane & 15;
  const int g = lane >> 4;
  const int r4 = g * 4;
  const int x0 = (g ^ (lrow & 7)) << 3;
  const int x1 = ((g + 4) ^ (lrow & 7)) << 3;

  f32x4 acc[4][4];
  const f32x4 z = {0.f, 0.f, 0.f, 0.f};
  for (int i = 0; i < 4; ++i)
    for (int j = 0; j < 4; ++j) acc[i][j] = z;

  for (int k0 = 0; k0 < HH; k0 += 64) {
#pragma unroll
    for (int it = 0; it < 4; ++it) {
      int idx = it * 256 + tid;
      int row = idx >> 3, seg = idx & 7;
      int sw = (seg ^ (row & 7)) << 3;
      int vrow = 192 * (2 * ny + (row >> 6)) + 128 + (row & 63);
      load_lds16(A + (size_t)(m0 + row) * HH + k0 + sw, &As[row * 64 + seg * 8]);
      load_lds16(Bt + (size_t)vrow * HH + k0 + sw, &Bs[row * 64 + seg * 8]);
    }
    __syncthreads();

    bf16x8 af[4], bfr[4];
#pragma unroll
    for (int i = 0; i < 4; ++i)
      af[i] = *reinterpret_cast<const bf16x8*>(&As[(wm + i * 16 + lrow) * 64 + x0]);
#pragma unroll
    for (int j = 0; j < 4; ++j)
      bfr[j] = *reinterpret_cast<const bf16x8*>(&Bs[(wn + j * 16 + lrow) * 64 + x0]);
#pragma unroll
    for (int i = 0; i < 4; ++i)
#pragma unroll
      for (int j = 0; j < 4; ++j)
        acc[i][j] = mfma16(af[i], bfr[j], acc[i][j]);
#pragma unroll
    for (int i = 0; i < 4; ++i)
      af[i] = *reinterpret_cast<const bf16x8*>(&As[(wm + i * 16 + lrow) * 64 + x1]);
#pragma unroll
    for (int j = 0; j < 4; ++j)
      bfr[j] = *reinterpret_cast<const bf16x8*>(&Bs[(wn + j * 16 + lrow) * 64 + x1]);
#pragma unroll
    for (int i = 0; i < 4; ++i)
#pragma unroll
      for (int j = 0; j < 4; ++j)
        acc[i][j] = mfma16(af[i], bfr[j], acc[i][j]);
    __syncthreads();
  }

  // ---- transposed epilogue: Ct[cl(128)][m(128)] bf16, XOR-swizzled m8 ----
  unsigned short* Ct = Sh;    // 32 KB, safe after last __syncthreads
  const int mb = wm + r4;     // + i*16; mo = mb&7 (0 or 4), stays in one 8-group
#pragma unroll
  for (int i = 0; i < 4; ++i) {
    int m = mb + i * 16;
    int m8 = m >> 3, mo = m & 7;
#pragma unroll
    for (int j = 0; j < 4; ++j) {
      int cl = wn + j * 16 + lrow;
      float bv = bias[192 * (2 * ny + (cl >> 6)) + 128 + (cl & 63)];
      uint2 w;
      w.x = cvtpk(acc[i][j][0] + bv, acc[i][j][1] + bv);
      w.y = cvtpk(acc[i][j][2] + bv, acc[i][j][3] + bv);
      *reinterpret_cast<uint2*>(&Ct[cl * 128 + ((m8 ^ (cl & 7)) << 3) + mo]) = w;
    }
  }
  __syncthreads();

  // ---- write out: vT row d, s contiguous (coalesced b128) ----
  const int bb = m0 >> 11;
  const int s0 = m0 & (SS - 1);
#pragma unroll
  for (int it = 0; it < 8; ++it) {
    int idx = it * 256 + tid;            // 2048 chunks of 8 elems
    int d = idx >> 4, s8 = idx & 15;
    bf16x8 v = *reinterpret_cast<const bf16x8*>(&Ct[d * 128 + ((s8 ^ (d & 7)) << 3)]);
    int head = 2 * ny + (d >> 6), dd = d & 63;
    *reinterpret_cast<bf16x8*>(
        vT + ((size_t)(bb * NHH + head) * HDD + dd) * SS + s0 + s8 * 8) = v;
  }
}

// ---------------- GEMM2 (R13, verified): 128x128, BK=64, XOR-swizzled LDS -----------
__global__ __launch_bounds__(256) void gemm_bt(const unsigned short* __restrict__ A,
                                               const unsigned short* __restrict__ Bt,
                                               const float* __restrict__ bias,
                                               float* __restrict__ Cv,
                                               int Ndim, int Kdim) {
  __shared__ __align__(16) unsigned short As[128 * 64];
  __shared__ __align__(16) unsigned short Bs[128 * 64];

  const int tid = threadIdx.x;
  const int wave = tid >> 6, lane = tid & 63;
  const int m0 = blockIdx.x * 128;
  const int n0 = blockIdx.y * 128;
  const int wm = (wave >> 1) * 64, wn = (wave & 1) * 64;
  const int lrow = lane & 15;
  const int g = lane >> 4;
  const int r4 = g * 4;
  const int x0 = (g ^ (lrow & 7)) << 3;
  const int x1 = ((g + 4) ^ (lrow & 7)) << 3;

  f32x4 acc[4][4];
  const f32x4 z = {0.f, 0.f, 0.f, 0.f};
  for (int i = 0; i < 4; ++i)
    for (int j = 0; j < 4; ++j) acc[i][j] = z;

  for (int k0 = 0; k0 < Kdim; k0 += 64) {
#pragma unroll
    for (int it = 0; it < 4; ++it) {
      int idx = it * 256 + tid;
      int row = idx >> 3, seg = idx & 7;
      int sw = (seg ^ (row & 7)) << 3;
      load_lds16(A + (size_t)(m0 + row) * Kdim + k0 + sw, &As[row * 64 + seg * 8]);
      load_lds16(Bt + (size_t)(n0 + row) * Kdim + k0 + sw, &Bs[row * 64 + seg * 8]);
    }
    __syncthreads();

    bf16x8 af[4], bfr[4];
#pragma unroll
    for (int i = 0; i < 4; ++i)
      af[i] = *reinterpret_cast<const bf16x8*>(&As[(wm + i * 16 + lrow) * 64 + x0]);
#pragma unroll
    for (int j = 0; j < 4; ++j)
      bfr[j] = *reinterpret_cast<const bf16x8*>(&Bs[(wn + j * 16 + lrow) * 64 + x0]);
#pragma unroll
    for (int i = 0; i < 4; ++i)
#pragma unroll
      for (int j = 0; j < 4; ++j)
        acc[i][j] = mfma16(af[i], bfr[j], acc[i][j]);
#pragma unroll
    for (int i = 0; i < 4; ++i)
      af[i] = *reinterpret_cast<const bf16x8*>(&As[(wm + i * 16 + lrow) * 64 + x1]);
#pragma unroll
    for (int j = 0; j < 4; ++j)
      bfr[j] = *reinterpret_cast<const bf16x8*>(&Bs[(wn + j * 16 + lrow) * 64 + x1]);
#pragma unroll
    for (int i = 0; i < 4; ++i)
#pragma unroll
      for (int j = 0; j < 4; ++j)
        acc[i][j] = mfma16(af[i], bfr[j], acc[i][j]);
    __syncthreads();
  }

#pragma unroll
  for (int i = 0; i < 4; ++i) {
#pragma unroll
    for (int j = 0; j < 4; ++j) {
      int col = n0 + wn + j * 16 + lrow;
      float bv = bias[col];
#pragma unroll
      for (int r = 0; r < 4; ++r) {
        int row = m0 + wm + i * 16 + r4 + r;
        Cv[(size_t)row * Ndim + col] = acc[i][j][r] + bv;
      }
    }
  }
}

// ---------------- Flash attention (R9/R17-exact; qk stride 2048) --------------------
__global__ __launch_bounds__(256, 4) void attn_kernel(const unsigned short* __restrict__ qk,
                                                      const unsigned short* __restrict__ vT,
                                                      const float* __restrict__ mask,
                                                      const unsigned char* __restrict__ flags,
                                                      unsigned short* __restrict__ ctx) {
  __shared__ __align__(16) unsigned short Ks[2][64 * 64];
  __shared__ __align__(16) unsigned short Vt[2][64 * 64];   // [d][s]
  __shared__ __align__(16) unsigned short QP[64 * 64];      // Q tile, then P (per-wave)

  const int tid = threadIdx.x, wave = tid >> 6, lane = tid & 63;
  const int ql = lane & 15;
  const int g = lane >> 4;
  const int q0 = blockIdx.x * 64;
  const int bh = blockIdx.y;
  const int b = bh / NHH, hh = bh % NHH;

  const unsigned short* qbase = qk + (size_t)(b * SS) * QKS + hh * 128;
  const unsigned short* kbase = qbase + 64;
  const unsigned short* vtbase = vT + ((size_t)(b * NHH + hh) * HDD) * SS;  // [d][s]
  const float* mbase = mask + (size_t)b * SS * SS;
  const unsigned char* fl = flags + ((size_t)b * 32 + blockIdx.x) * 32;

  const int srow = tid >> 3, sseg = tid & 7;
  const int swst = (sseg ^ (srow & 7)) << 3;

  // ---- prologue: stage Q, K0, V0 ----
  load_lds16(qbase + (size_t)(q0 + srow) * QKS + swst, &QP[srow * 64 + sseg * 8]);
  load_lds16(qbase + (size_t)(q0 + 32 + srow) * QKS + swst, &QP[(32 + srow) * 64 + sseg * 8]);
  load_lds16(kbase + (size_t)srow * QKS + swst, &Ks[0][srow * 64 + sseg * 8]);
  load_lds16(kbase + (size_t)(32 + srow) * QKS + swst, &Ks[0][(32 + srow) * 64 + sseg * 8]);
  load_lds16(vtbase + (size_t)srow * SS + swst, &Vt[0][srow * 64 + sseg * 8]);
  load_lds16(vtbase + (size_t)(32 + srow) * SS + swst, &Vt[0][(32 + srow) * 64 + sseg * 8]);
  __syncthreads();

  // ---- hoist Q fragments ----
  const int qrow = wave * 16 + ql;
  const bf16x8 qf0 = *reinterpret_cast<const bf16x8*>(
      &QP[qrow * 64 + ((g ^ (qrow & 7)) << 3)]);
  const bf16x8 qf1 = *reinterpret_cast<const bf16x8*>(
      &QP[qrow * 64 + (((g + 4) ^ (qrow & 7)) << 3)]);
  __syncthreads();   // everyone done reading Q before P overwrites it

  // ---- precomputed loop-invariant LDS pointers ----
  const int s0 = (g ^ (ql & 7)) << 3;
  const int s1 = ((g + 4) ^ (ql & 7)) << 3;
  const unsigned short* KrA = &Ks[0][ql * 64 + s0];   // + CUR*4096 + n*1024
  const unsigned short* KrB = &Ks[0][ql * 64 + s1];
  const unsigned short* VrA = &Vt[0][ql * 64 + s0];   // + CUR*4096 + fd*1024
  const unsigned short* VrB = &Vt[0][ql * 64 + s1];
  unsigned short* Ps = &QP[wave * 1024];
  const int X = (ql & 7) << 3;
  unsigned short* Pw0 = &Ps[ql * 64 + ((4 * g) ^ X)];
  unsigned short* Pw1 = &Ps[ql * 64 + ((16 + 4 * g) ^ X)];
  unsigned short* Pw2 = &Ps[ql * 64 + ((32 + 4 * g) ^ X)];
  unsigned short* Pw3 = &Ps[ql * 64 + ((48 + 4 * g) ^ X)];
  const unsigned short* Pr0 = &Ps[ql * 64 + ((8 * g) ^ X)];
  const unsigned short* Pr1 = &Ps[ql * 64 + ((32 + 8 * g) ^ X)];

  // ---- loop-carried global prefetch pointers ----
  const unsigned short* kpre = kbase + (size_t)(64 + srow) * QKS + swst;
  const unsigned short* vpre = vtbase + (size_t)srow * SS + 64 + swst;

  f32x4 oacc[4];
  const f32x4 z = {0.f, 0.f, 0.f, 0.f};
  for (int fd = 0; fd < 4; ++fd) oacc[fd] = z;
  float lsum = 0.f;
  const float C2 = 0.125f * LOG2E;

#define TILE_BODY(CUR_, KT_, HAVENEXT_)                                         \
  {                                                                             \
    const int kt_ = (KT_);                                                      \
    if (HAVENEXT_) {                                                            \
      load_lds16(kpre, &Ks[(CUR_)^1][srow * 64 + sseg * 8]);                    \
      load_lds16(kpre + 32 * QKS, &Ks[(CUR_)^1][(32 + srow) * 64 + sseg * 8]);  \
      load_lds16(vpre, &Vt[(CUR_)^1][srow * 64 + sseg * 8]);                    \
      load_lds16(vpre + 32 * SS, &Vt[(CUR_)^1][(32 + srow) * 64 + sseg * 8]);   \
    }                                                                           \
    kpre += 64 * QKS; vpre += 64;                                               \
    f32x4 sacc[4];                                                              \
    __builtin_amdgcn_s_setprio(1);                                              \
    _Pragma("unroll")                                                           \
    for (int n = 0; n < 4; ++n) {                                               \
      bf16x8 k0 = *reinterpret_cast<const bf16x8*>(KrA + (CUR_)*4096 + n*1024); \
      bf16x8 k1 = *reinterpret_cast<const bf16x8*>(KrB + (CUR_)*4096 + n*1024); \
      sacc[n] = mfma16(k0, qf0, z);                                             \
      sacc[n] = mfma16(k1, qf1, sacc[n]);                                       \
    }                                                                           \
    __builtin_amdgcn_s_setprio(0);                                              \
    bf16x8 bv00 = *reinterpret_cast<const bf16x8*>(VrA + (CUR_)*4096 + 0*1024); \
    bf16x8 bv10 = *reinterpret_cast<const bf16x8*>(VrB + (CUR_)*4096 + 0*1024); \
    bf16x8 bv01 = *reinterpret_cast<const bf16x8*>(VrA + (CUR_)*4096 + 1*1024); \
    bf16x8 bv11 = *reinterpret_cast<const bf16x8*>(VrB + (CUR_)*4096 + 1*1024); \
    bf16x8 bv02 = *reinterpret_cast<const bf16x8*>(VrA + (CUR_)*4096 + 2*1024); \
    bf16x8 bv12 = *reinterpret_cast<const bf16x8*>(VrB + (CUR_)*4096 + 2*1024); \
    bf16x8 bv03 = *reinterpret_cast<const bf16x8*>(VrA + (CUR_)*4096 + 3*1024); \
    bf16x8 bv13 = *reinterpret_cast<const bf16x8*>(VrB + (CUR_)*4096 + 3*1024); \
    const bool allones = fl[kt_] != 0;                                          \
    float pv[4][4];                                                             \
    if (allones) {                                                              \
      _Pragma("unroll")                                                         \
      for (int n = 0; n < 4; ++n)                                               \
        _Pragma("unroll")                                                       \
        for (int r = 0; r < 4; ++r)                                             \
          pv[n][r] = exp2f(sacc[n][r] * C2);                                    \
    } else {                                                                    \
      int qq = q0 + wave * 16 + ql;                                             \
      _Pragma("unroll")                                                         \
      for (int n = 0; n < 4; ++n)                                               \
        _Pragma("unroll")                                                       \
        for (int r = 0; r < 4; ++r) {                                           \
          int kk = kt_ * 64 + 16 * n + 4 * g + r;                               \
          float mv = mbase[(size_t)qq * SS + kk];                               \
          float s = sacc[n][r] * 0.125f;                                        \
          pv[n][r] = exp2f((s * mv - 10000.f * (1.f - mv)) * LOG2E);            \
        }                                                                       \
    }                                                                           \
    { uint2 w; w.x = cvtpk(pv[0][0], pv[0][1]); w.y = cvtpk(pv[0][2], pv[0][3]);\
      *reinterpret_cast<uint2*>(Pw0) = w; }                                     \
    { uint2 w; w.x = cvtpk(pv[1][0], pv[1][1]); w.y = cvtpk(pv[1][2], pv[1][3]);\
      *reinterpret_cast<uint2*>(Pw1) = w; }                                     \
    { uint2 w; w.x = cvtpk(pv[2][0], pv[2][1]); w.y = cvtpk(pv[2][2], pv[2][3]);\
      *reinterpret_cast<uint2*>(Pw2) = w; }                                     \
    { uint2 w; w.x = cvtpk(pv[3][0], pv[3][1]); w.y = cvtpk(pv[3][2], pv[3][3]);\
      *reinterpret_cast<uint2*>(Pw3) = w; }                                     \
    {                                                                           \
      float t00 = (pv[0][0] + pv[0][1]) + (pv[0][2] + pv[0][3]);                \
      float t01 = (pv[1][0] + pv[1][1]) + (pv[1][2] + pv[1][3]);                \
      float t10 = (pv[2][0] + pv[2][1]) + (pv[2][2] + pv[2][3]);                \
      float t11 = (pv[3][0] + pv[3][1]) + (pv[3][2] + pv[3][3]);                \
      lsum += (t00 + t01) + (t10 + t11);                                        \
    }                                                                           \
    bf16x8 pa0 = *reinterpret_cast<const bf16x8*>(Pr0);                         \
    bf16x8 pa1 = *reinterpret_cast<const bf16x8*>(Pr1);                         \
    __builtin_amdgcn_s_setprio(1);                                              \
    oacc[0] = mfma16(pa0, bv00, oacc[0]);                                       \
    oacc[1] = mfma16(pa0, bv01, oacc[1]);                                       \
    oacc[2] = mfma16(pa0, bv02, oacc[2]);                                       \
    oacc[3] = mfma16(pa0, bv03, oacc[3]);                                       \
    oacc[0] = mfma16(pa1, bv10, oacc[0]);                                       \
    oacc[1] = mfma16(pa1, bv11, oacc[1]);                                       \
    oacc[2] = mfma16(pa1, bv12, oacc[2]);                                       \
    oacc[3] = mfma16(pa1, bv13, oacc[3]);                                       \
    __builtin_amdgcn_s_setprio(0);                                              \
    __syncthreads();                                                            \
  }

  for (int kt = 0; kt < NT; kt += 2) {
    TILE_BODY(0, kt, true)                 // kt <= 30 -> kt+1 < 32 always
    TILE_BODY(1, kt + 1, (kt + 2 < NT))
  }
#undef TILE_BODY

  // ---- epilogue: reduce l across groups, gather per-row, store ----
  float lrun = lsum;
  lrun += __shfl_xor(lrun, 16, 64);
  lrun += __shfl_xor(lrun, 32, 64);
  float invl = 1.f / lrun;   // valid for q = ql at this lane
#pragma unroll
  for (int r = 0; r < 4; ++r) {
    float inv = __shfl(invl, g * 4 + r, 64);
    int qq = q0 + wave * 16 + g * 4 + r;
    unsigned short* cp = ctx + (size_t)(b * SS + qq) * HH + hh * HDD;
#pragma unroll
    for (int fd = 0; fd < 4; ++fd)
      cp[fd * 16 + ql] = f2bfu(oacc[fd][r] * inv);
  }
}

extern "C" void kernel_launch(void* const* d_in, const int* in_sizes, int n_in,
                              void* d_out, int out_size, void* d_ws, size_t ws_size,
                              hipStream_t stream) {
  const float* hs      = (const float*)d_in[0];
  const float* mask    = (const float*)d_in[1];
  const float* qkv_w   = (const float*)d_in[2];
  const float* qkv_b   = (const float*)d_in[3];
  const float* dense_w = (const float*)d_in[4];
  const float* dense_b = (const float*)d_in[5];
  float* out = (float*)d_out;

  char* ws = (char*)d_ws;
  unsigned short* hs_b     = (unsigned short*)(ws);                 // 4096x1024 (8MB)
  unsigned short* qkvw_b   = (unsigned short*)(ws + 8388608);       // 3072x1024 (6MB)
  unsigned short* densew_b = (unsigned short*)(ws + 14680064);      // 1024x1024 (2MB)
  unsigned short* qk_b     = (unsigned short*)(ws + 16777216);      // 4096x2048 (16MB)
  unsigned short* ctx_b    = (unsigned short*)(ws + 41943040);      // 4096x1024 (8MB)
  unsigned char*  flags    = (unsigned char*)(ws + 50331648);       // 2048 B
  unsigned short* vT_b     = (unsigned short*)(ws + 50335744);      // 8MB

  prep_kernel<<<4096, 256, 0, stream>>>(mask, flags,
                                        hs, hs_b, (MM * HH) / 4,
                                        qkv_w, qkvw_b, (N1 * HH) / 4,
                                        dense_w, densew_b, (HH * HH) / 4);

  // GEMM1 split: Q/K -> packed qk (stride 2048); V -> vT (transposed epilogue)
  gemm_qk<<<dim3(MM / 128, NHH), 256, 0, stream>>>(hs_b, qkvw_b, qkv_b, qk_b);
  gemm_v<<<dim3(MM / 128, NHH / 2), 256, 0, stream>>>(hs_b, qkvw_b, qkv_b, vT_b);

  attn_kernel<<<dim3(SS / 64, BB * NHH), 256, 0, stream>>>(
      qk_b, vT_b, mask, flags, ctx_b);

  gemm_bt<<<dim3(MM / 128, HH / 128), 256, 0, stream>>>(
      ctx_b, densew_b, dense_b, out, HH, HH);
}

// Round 20
// 146.893 us; speedup vs baseline: 1.2567x; 1.0248x over previous
//
#include <hip/hip_runtime.h>
#include <hip/hip_bf16.h>
#include <stdint.h>

#define BB 2
#define SS 2048
#define HH 1024
#define NHH 16
#define HDD 64
#define MM (BB*SS)      // 4096
#define N1 (3*HH)       // 3072
#define NT (SS/64)      // 32 kv tiles
#define LOG2E 1.44269504f

using bf16 = __hip_bfloat16;
typedef __attribute__((ext_vector_type(8))) short bf16x8;
typedef __attribute__((ext_vector_type(4))) float f32x4;

__device__ inline unsigned short f2bfu(float f) {
  union { bf16 h; unsigned short u; } c;
  c.h = __float2bfloat16(f);
  return c.u;
}

// hardware packed f32->bf16 (RNE), src0 -> low16, src1 -> high16 (T12 recipe)
__device__ inline unsigned int cvtpk(float lo, float hi) {
  unsigned int r;
  asm("v_cvt_pk_bf16_f32 %0, %1, %2" : "=v"(r) : "v"(lo), "v"(hi));
  return r;
}

__device__ inline void load_lds16(const void* g, void* l) {
  __builtin_amdgcn_global_load_lds(
      (const __attribute__((address_space(1))) void*)g,
      (__attribute__((address_space(3))) void*)l, 16, 0, 0);
}

__device__ inline f32x4 mfma16(bf16x8 a, bf16x8 b, f32x4 c) {
  return __builtin_amdgcn_mfma_f32_16x16x32_bf16(a, b, c, 0, 0, 0);
}

// ---------------- prep: mask tile flags (blocks 0..2047) + fp32->bf16 cvt ----------
__global__ __launch_bounds__(256) void prep_kernel(const float* __restrict__ mask,
                                                   unsigned char* __restrict__ flags,
                                                   const float* __restrict__ a,
                                                   unsigned short* __restrict__ ao, int na4,
                                                   const float* __restrict__ bsrc,
                                                   unsigned short* __restrict__ bo, int nb4,
                                                   const float* __restrict__ c,
                                                   unsigned short* __restrict__ co, int nc4) {
  if (blockIdx.x < 2048) {
    // mask tile flags: 1 if 64x64 tile is all ones
    int t = blockIdx.x;
    int b = t >> 10, qt = (t >> 5) & 31, kt = t & 31;
    const float* mb = mask + ((size_t)b * SS + qt * 64) * SS + kt * 64;
    int row = threadIdx.x >> 2, c0 = (threadIdx.x & 3) * 16;
    int ok = 1;
#pragma unroll
    for (int j = 0; j < 4; ++j) {
      float4 v = *reinterpret_cast<const float4*>(mb + (size_t)row * SS + c0 + j * 4);
      ok &= (v.x == 1.f) & (v.y == 1.f) & (v.z == 1.f) & (v.w == 1.f);
    }
    ok = __all(ok);
    __shared__ int s[4];
    if ((threadIdx.x & 63) == 0) s[threadIdx.x >> 6] = ok;
    __syncthreads();
    if (threadIdx.x == 0) flags[t] = (unsigned char)(s[0] & s[1] & s[2] & s[3]);
    return;
  }
  // fused convert over 3 buffers
  int total = na4 + nb4 + nc4;
  int nblk = gridDim.x - 2048;
  int st = nblk * blockDim.x;
  for (int i = (blockIdx.x - 2048) * blockDim.x + threadIdx.x; i < total; i += st) {
    const float* in; unsigned short* out; int j = i;
    if (j < na4) { in = a; out = ao; }
    else if (j < na4 + nb4) { j -= na4; in = bsrc; out = bo; }
    else { j -= na4 + nb4; in = c; out = co; }
    float4 v = reinterpret_cast<const float4*>(in)[j];
    ushort4 o;
    o.x = f2bfu(v.x); o.y = f2bfu(v.y); o.z = f2bfu(v.z); o.w = f2bfu(v.w);
    reinterpret_cast<ushort4*>(out)[j] = o;
  }
}

// ---------------- V transpose: mixed V-cols -> vT[b][h][d][s] ----------------
__global__ __launch_bounds__(256) void vtrans_kernel(const unsigned short* __restrict__ mixed,
                                                     unsigned short* __restrict__ vT) {
  __shared__ unsigned short t[64 * 72];
  const int st = blockIdx.x, bh = blockIdx.y;
  const int b = bh >> 4, h = bh & 15;
  const int r = threadIdx.x >> 2, c0 = (threadIdx.x & 3) * 16;

  const unsigned short* src = mixed + ((size_t)(b * SS) + st * 64) * N1 + h * 192 + 128;
  union { bf16x8 v; unsigned short u[8]; } A, B;
  A.v = *reinterpret_cast<const bf16x8*>(src + (size_t)r * N1 + c0);
  B.v = *reinterpret_cast<const bf16x8*>(src + (size_t)r * N1 + c0 + 8);
#pragma unroll
  for (int j = 0; j < 8; ++j) t[(c0 + j) * 72 + r] = A.u[j];
#pragma unroll
  for (int j = 0; j < 8; ++j) t[(c0 + 8 + j) * 72 + r] = B.u[j];
  __syncthreads();

  unsigned short* dst = vT + ((size_t)bh * HDD + r) * SS + st * 64 + c0;
  bf16x8 o0 = *reinterpret_cast<const bf16x8*>(&t[r * 72 + c0]);
  bf16x8 o1 = *reinterpret_cast<const bf16x8*>(&t[r * 72 + c0 + 8]);
  *reinterpret_cast<bf16x8*>(dst) = o0;
  *reinterpret_cast<bf16x8*>(dst + 8) = o1;
}

// ---------------- GEMM (R13, verified): 128x128, BK=64, XOR-swizzled LDS ------------
template <bool OUT_BF16>
__global__ __launch_bounds__(256) void gemm_bt(const unsigned short* __restrict__ A,
                                               const unsigned short* __restrict__ Bt,
                                               const float* __restrict__ bias,
                                               void* __restrict__ Cv,
                                               int Ndim, int Kdim) {
  __shared__ __align__(16) unsigned short As[128 * 64];
  __shared__ __align__(16) unsigned short Bs[128 * 64];

  const int tid = threadIdx.x;
  const int wave = tid >> 6, lane = tid & 63;
  const int m0 = blockIdx.x * 128;
  const int n0 = blockIdx.y * 128;
  const int wm = (wave >> 1) * 64, wn = (wave & 1) * 64;
  const int lrow = lane & 15;
  const int g = lane >> 4;
  const int r4 = (lane >> 4) * 4;
  const int x0 = (g ^ (lrow & 7)) << 3;
  const int x1 = ((g + 4) ^ (lrow & 7)) << 3;

  f32x4 acc[4][4];
  const f32x4 z = {0.f, 0.f, 0.f, 0.f};
  for (int i = 0; i < 4; ++i)
    for (int j = 0; j < 4; ++j) acc[i][j] = z;

  for (int k0 = 0; k0 < Kdim; k0 += 64) {
#pragma unroll
    for (int it = 0; it < 4; ++it) {
      int idx = it * 256 + tid;
      int row = idx >> 3, seg = idx & 7;
      int sw = (seg ^ (row & 7)) << 3;
      load_lds16(A + (size_t)(m0 + row) * Kdim + k0 + sw, &As[row * 64 + seg * 8]);
      load_lds16(Bt + (size_t)(n0 + row) * Kdim + k0 + sw, &Bs[row * 64 + seg * 8]);
    }
    __syncthreads();

    bf16x8 af[4], bfr[4];
#pragma unroll
    for (int i = 0; i < 4; ++i)
      af[i] = *reinterpret_cast<const bf16x8*>(&As[(wm + i * 16 + lrow) * 64 + x0]);
#pragma unroll
    for (int j = 0; j < 4; ++j)
      bfr[j] = *reinterpret_cast<const bf16x8*>(&Bs[(wn + j * 16 + lrow) * 64 + x0]);
#pragma unroll
    for (int i = 0; i < 4; ++i)
#pragma unroll
      for (int j = 0; j < 4; ++j)
        acc[i][j] = mfma16(af[i], bfr[j], acc[i][j]);
#pragma unroll
    for (int i = 0; i < 4; ++i)
      af[i] = *reinterpret_cast<const bf16x8*>(&As[(wm + i * 16 + lrow) * 64 + x1]);
#pragma unroll
    for (int j = 0; j < 4; ++j)
      bfr[j] = *reinterpret_cast<const bf16x8*>(&Bs[(wn + j * 16 + lrow) * 64 + x1]);
#pragma unroll
    for (int i = 0; i < 4; ++i)
#pragma unroll
      for (int j = 0; j < 4; ++j)
        acc[i][j] = mfma16(af[i], bfr[j], acc[i][j]);
    __syncthreads();
  }

#pragma unroll
  for (int i = 0; i < 4; ++i) {
#pragma unroll
    for (int j = 0; j < 4; ++j) {
      int col = n0 + wn + j * 16 + lrow;
      float bv = bias[col];
#pragma unroll
      for (int r = 0; r < 4; ++r) {
        int row = m0 + wm + i * 16 + r4 + r;
        float v = acc[i][j][r] + bv;
        if (OUT_BF16) {
          ((unsigned short*)Cv)[(size_t)row * Ndim + col] = f2bfu(v);
        } else {
          ((float*)Cv)[(size_t)row * Ndim + col] = v;
        }
      }
    }
  }
}

// ---------------- Flash attention (R9 structure + early V-fragment loads) -----------
// Block 256 = 4 waves; Q-tile 64 (wave owns 16 q-rows); KVBLK 64; grid (32, B*NH).
// Swapped QK^T (mfma16(K,Q) -> D[krow][q], q=lane&15), max-free softmax,
// 2x-unrolled kt loop, precomputed LDS pointers, cvt_pk P-pack, deferred l-sum.
__global__ __launch_bounds__(256, 4) void attn_kernel(const unsigned short* __restrict__ mixed,
                                                      const unsigned short* __restrict__ vT,
                                                      const float* __restrict__ mask,
                                                      const unsigned char* __restrict__ flags,
                                                      unsigned short* __restrict__ ctx) {
  __shared__ __align__(16) unsigned short Ks[2][64 * 64];
  __shared__ __align__(16) unsigned short Vt[2][64 * 64];   // [d][s]
  __shared__ __align__(16) unsigned short QP[64 * 64];      // Q tile, then P (per-wave)

  const int tid = threadIdx.x, wave = tid >> 6, lane = tid & 63;
  const int ql = lane & 15;
  const int g = lane >> 4;
  const int q0 = blockIdx.x * 64;
  const int bh = blockIdx.y;
  const int b = bh / NHH, hh = bh % NHH;

  const unsigned short* qbase = mixed + (size_t)(b * SS) * N1 + hh * 192;
  const unsigned short* kbase = qbase + 64;
  const unsigned short* vtbase = vT + ((size_t)(b * NHH + hh) * HDD) * SS;  // [d][s]
  const float* mbase = mask + (size_t)b * SS * SS;
  const unsigned char* fl = flags + ((size_t)b * 32 + blockIdx.x) * 32;

  const int srow = tid >> 3, sseg = tid & 7;
  const int swst = (sseg ^ (srow & 7)) << 3;

  // ---- prologue: stage Q, K0, V0 ----
  load_lds16(qbase + (size_t)(q0 + srow) * N1 + swst, &QP[srow * 64 + sseg * 8]);
  load_lds16(qbase + (size_t)(q0 + 32 + srow) * N1 + swst, &QP[(32 + srow) * 64 + sseg * 8]);
  load_lds16(kbase + (size_t)srow * N1 + swst, &Ks[0][srow * 64 + sseg * 8]);
  load_lds16(kbase + (size_t)(32 + srow) * N1 + swst, &Ks[0][(32 + srow) * 64 + sseg * 8]);
  load_lds16(vtbase + (size_t)srow * SS + swst, &Vt[0][srow * 64 + sseg * 8]);
  load_lds16(vtbase + (size_t)(32 + srow) * SS + swst, &Vt[0][(32 + srow) * 64 + sseg * 8]);
  __syncthreads();

  // ---- hoist Q fragments ----
  const int qrow = wave * 16 + ql;
  const bf16x8 qf0 = *reinterpret_cast<const bf16x8*>(
      &QP[qrow * 64 + ((g ^ (qrow & 7)) << 3)]);
  const bf16x8 qf1 = *reinterpret_cast<const bf16x8*>(
      &QP[qrow * 64 + (((g + 4) ^ (qrow & 7)) << 3)]);
  __syncthreads();   // everyone done reading Q before P overwrites it

  // ---- precomputed loop-invariant LDS pointers ----
  const int s0 = (g ^ (ql & 7)) << 3;
  const int s1 = ((g + 4) ^ (ql & 7)) << 3;
  const unsigned short* KrA = &Ks[0][ql * 64 + s0];   // + CUR*4096 + n*1024
  const unsigned short* KrB = &Ks[0][ql * 64 + s1];
  const unsigned short* VrA = &Vt[0][ql * 64 + s0];   // + CUR*4096 + fd*1024
  const unsigned short* VrB = &Vt[0][ql * 64 + s1];
  unsigned short* Ps = &QP[wave * 1024];
  const int X = (ql & 7) << 3;
  unsigned short* Pw0 = &Ps[ql * 64 + ((4 * g) ^ X)];
  unsigned short* Pw1 = &Ps[ql * 64 + ((16 + 4 * g) ^ X)];
  unsigned short* Pw2 = &Ps[ql * 64 + ((32 + 4 * g) ^ X)];
  unsigned short* Pw3 = &Ps[ql * 64 + ((48 + 4 * g) ^ X)];
  const unsigned short* Pr0 = &Ps[ql * 64 + ((8 * g) ^ X)];
  const unsigned short* Pr1 = &Ps[ql * 64 + ((32 + 8 * g) ^ X)];

  // ---- loop-carried global prefetch pointers ----
  const unsigned short* kpre = kbase + (size_t)(64 + srow) * N1 + swst;
  const unsigned short* vpre = vtbase + (size_t)srow * SS + 64 + swst;

  f32x4 oacc[4];
  const f32x4 z = {0.f, 0.f, 0.f, 0.f};
  for (int fd = 0; fd < 4; ++fd) oacc[fd] = z;
  float lsum = 0.f;
  const float C2 = 0.125f * LOG2E;

#define TILE_BODY(CUR_, KT_, HAVENEXT_)                                         \
  {                                                                             \
    const int kt_ = (KT_);                                                      \
    if (HAVENEXT_) {                                                            \
      load_lds16(kpre, &Ks[(CUR_)^1][srow * 64 + sseg * 8]);                    \
      load_lds16(kpre + 32 * N1, &Ks[(CUR_)^1][(32 + srow) * 64 + sseg * 8]);   \
      load_lds16(vpre, &Vt[(CUR_)^1][srow * 64 + sseg * 8]);                    \
      load_lds16(vpre + 32 * SS, &Vt[(CUR_)^1][(32 + srow) * 64 + sseg * 8]);   \
    }                                                                           \
    kpre += 64 * N1; vpre += 64;                                                \
    f32x4 sacc[4];                                                              \
    __builtin_amdgcn_s_setprio(1);                                              \
    _Pragma("unroll")                                                           \
    for (int n = 0; n < 4; ++n) {                                               \
      bf16x8 k0 = *reinterpret_cast<const bf16x8*>(KrA + (CUR_)*4096 + n*1024); \
      bf16x8 k1 = *reinterpret_cast<const bf16x8*>(KrB + (CUR_)*4096 + n*1024); \
      sacc[n] = mfma16(k0, qf0, z);                                             \
      sacc[n] = mfma16(k1, qf1, sacc[n]);                                       \
    }                                                                           \
    __builtin_amdgcn_s_setprio(0);                                              \
    /* early V-fragment loads: LDS latency hides under softmax VALU */          \
    bf16x8 bv00 = *reinterpret_cast<const bf16x8*>(VrA + (CUR_)*4096 + 0*1024); \
    bf16x8 bv10 = *reinterpret_cast<const bf16x8*>(VrB + (CUR_)*4096 + 0*1024); \
    bf16x8 bv01 = *reinterpret_cast<const bf16x8*>(VrA + (CUR_)*4096 + 1*1024); \
    bf16x8 bv11 = *reinterpret_cast<const bf16x8*>(VrB + (CUR_)*4096 + 1*1024); \
    bf16x8 bv02 = *reinterpret_cast<const bf16x8*>(VrA + (CUR_)*4096 + 2*1024); \
    bf16x8 bv12 = *reinterpret_cast<const bf16x8*>(VrB + (CUR_)*4096 + 2*1024); \
    bf16x8 bv03 = *reinterpret_cast<const bf16x8*>(VrA + (CUR_)*4096 + 3*1024); \
    bf16x8 bv13 = *reinterpret_cast<const bf16x8*>(VrB + (CUR_)*4096 + 3*1024); \
    const bool allones = fl[kt_] != 0;                                          \
    float pv[4][4];                                                             \
    if (allones) {                                                              \
      _Pragma("unroll")                                                         \
      for (int n = 0; n < 4; ++n)                                               \
        _Pragma("unroll")                                                       \
        for (int r = 0; r < 4; ++r)                                             \
          pv[n][r] = exp2f(sacc[n][r] * C2);                                    \
    } else {                                                                    \
      int qq = q0 + wave * 16 + ql;                                             \
      _Pragma("unroll")                                                         \
      for (int n = 0; n < 4; ++n)                                               \
        _Pragma("unroll")                                                       \
        for (int r = 0; r < 4; ++r) {                                           \
          int kk = kt_ * 64 + 16 * n + 4 * g + r;                               \
          float mv = mbase[(size_t)qq * SS + kk];                               \
          float s = sacc[n][r] * 0.125f;                                        \
          pv[n][r] = exp2f((s * mv - 10000.f * (1.f - mv)) * LOG2E);            \
        }                                                                       \
    }                                                                           \
    { uint2 w; w.x = cvtpk(pv[0][0], pv[0][1]); w.y = cvtpk(pv[0][2], pv[0][3]);\
      *reinterpret_cast<uint2*>(Pw0) = w; }                                     \
    { uint2 w; w.x = cvtpk(pv[1][0], pv[1][1]); w.y = cvtpk(pv[1][2], pv[1][3]);\
      *reinterpret_cast<uint2*>(Pw1) = w; }                                     \
    { uint2 w; w.x = cvtpk(pv[2][0], pv[2][1]); w.y = cvtpk(pv[2][2], pv[2][3]);\
      *reinterpret_cast<uint2*>(Pw2) = w; }                                     \
    { uint2 w; w.x = cvtpk(pv[3][0], pv[3][1]); w.y = cvtpk(pv[3][2], pv[3][3]);\
      *reinterpret_cast<uint2*>(Pw3) = w; }                                     \
    /* lsum tree after P-writes: covers ds_write->ds_read gap */                \
    {                                                                           \
      float t00 = (pv[0][0] + pv[0][1]) + (pv[0][2] + pv[0][3]);                \
      float t01 = (pv[1][0] + pv[1][1]) + (pv[1][2] + pv[1][3]);                \
      float t10 = (pv[2][0] + pv[2][1]) + (pv[2][2] + pv[2][3]);                \
      float t11 = (pv[3][0] + pv[3][1]) + (pv[3][2] + pv[3][3]);                \
      lsum += (t00 + t01) + (t10 + t11);                                        \
    }                                                                           \
    bf16x8 pa0 = *reinterpret_cast<const bf16x8*>(Pr0);                         \
    bf16x8 pa1 = *reinterpret_cast<const bf16x8*>(Pr1);                         \
    __builtin_amdgcn_s_setprio(1);                                              \
    oacc[0] = mfma16(pa0, bv00, oacc[0]);                                       \
    oacc[1] = mfma16(pa0, bv01, oacc[1]);                                       \
    oacc[2] = mfma16(pa0, bv02, oacc[2]);                                       \
    oacc[3] = mfma16(pa0, bv03, oacc[3]);                                       \
    oacc[0] = mfma16(pa1, bv10, oacc[0]);                                       \
    oacc[1] = mfma16(pa1, bv11, oacc[1]);                                       \
    oacc[2] = mfma16(pa1, bv12, oacc[2]);                                       \
    oacc[3] = mfma16(pa1, bv13, oacc[3]);                                       \
    __builtin_amdgcn_s_setprio(0);                                              \
    __syncthreads();                                                            \
  }

  for (int kt = 0; kt < NT; kt += 2) {
    TILE_BODY(0, kt, true)                 // kt <= 30 -> kt+1 < 32 always
    TILE_BODY(1, kt + 1, (kt + 2 < NT))
  }
#undef TILE_BODY

  // ---- epilogue: reduce l across groups, gather per-row, store ----
  float lrun = lsum;
  lrun += __shfl_xor(lrun, 16, 64);
  lrun += __shfl_xor(lrun, 32, 64);
  float invl = 1.f / lrun;   // valid for q = ql at this lane
#pragma unroll
  for (int r = 0; r < 4; ++r) {
    float inv = __shfl(invl, g * 4 + r, 64);
    int qq = q0 + wave * 16 + g * 4 + r;
    unsigned short* cp = ctx + (size_t)(b * SS + qq) * HH + hh * HDD;
#pragma unroll
    for (int fd = 0; fd < 4; ++fd)
      cp[fd * 16 + ql] = f2bfu(oacc[fd][r] * inv);
  }
}

extern "C" void kernel_launch(void* const* d_in, const int* in_sizes, int n_in,
                              void* d_out, int out_size, void* d_ws, size_t ws_size,
                              hipStream_t stream) {
  const float* hs      = (const float*)d_in[0];
  const float* mask    = (const float*)d_in[1];
  const float* qkv_w   = (const float*)d_in[2];
  const float* qkv_b   = (const float*)d_in[3];
  const float* dense_w = (const float*)d_in[4];
  const float* dense_b = (const float*)d_in[5];
  float* out = (float*)d_out;

  char* ws = (char*)d_ws;
  unsigned short* hs_b     = (unsigned short*)(ws);                 // 4096x1024 (8MB)
  unsigned short* qkvw_b   = (unsigned short*)(ws + 8388608);       // 3072x1024 (6MB)
  unsigned short* densew_b = (unsigned short*)(ws + 14680064);      // 1024x1024 (2MB)
  unsigned short* mixed_b  = (unsigned short*)(ws + 16777216);      // 4096x3072 (24MB)
  unsigned short* ctx_b    = (unsigned short*)(ws + 41943040);      // 4096x1024 (8MB)
  unsigned char*  flags    = (unsigned char*)(ws + 50331648);       // 2048 B
  unsigned short* vT_b     = (unsigned short*)(ws + 50335744);      // 8MB

  // prep: mask flags (blocks 0..2047) + fused cvt (blocks 2048..4095)
  prep_kernel<<<4096, 256, 0, stream>>>(mask, flags,
                                        hs, hs_b, (MM * HH) / 4,
                                        qkv_w, qkvw_b, (N1 * HH) / 4,
                                        dense_w, densew_b, (HH * HH) / 4);

  gemm_bt<true><<<dim3(MM / 128, N1 / 128), 256, 0, stream>>>(
      hs_b, qkvw_b, qkv_b, mixed_b, N1, HH);

  vtrans_kernel<<<dim3(SS / 64, BB * NHH), 256, 0, stream>>>(mixed_b, vT_b);

  attn_kernel<<<dim3(SS / 64, BB * NHH), 256, 0, stream>>>(
      mixed_b, vT_b, mask, flags, ctx_b);

  gemm_bt<false><<<dim3(MM / 128, HH / 128), 256, 0, stream>>>(
      ctx_b, densew_b, dense_b, out, HH, HH);
}